// Round 3
// baseline (1145.755 us; speedup 1.0000x reference)
//
#include <hip/hip_runtime.h>
#include <hip/hip_bf16.h>

typedef __bf16 bf16x8 __attribute__((ext_vector_type(8)));
typedef float  f32x4  __attribute__((ext_vector_type(4)));
typedef unsigned int uint;

#define MFMA(a, b, c) __builtin_amdgcn_mfma_f32_16x16x32_bf16((a), (b), (c), 0, 0, 0)

typedef __attribute__((address_space(1))) void* as1_vp;
typedef __attribute__((address_space(3))) void* as3_vp;

__device__ __forceinline__ void g2lds16(const void* g, void* lds) {
  __builtin_amdgcn_global_load_lds((as1_vp)(unsigned long long)g,
                                   (as3_vp)(unsigned int)(unsigned long long)lds,
                                   16, 0, 0);
}

__device__ __forceinline__ unsigned short bfbits(float x) {
  return __builtin_bit_cast(unsigned short, __float2bfloat16(x));
}

// ---------------------------------------------------------------- convert
__global__ void cvt_f32_bf16(const float* __restrict__ in,
                             __hip_bfloat16* __restrict__ out, int n4) {
  int i = blockIdx.x * blockDim.x + threadIdx.x;
  if (i >= n4) return;
  float4 v = ((const float4*)in)[i];
  ushort4 u;
  u.x = bfbits(v.x); u.y = bfbits(v.y); u.z = bfbits(v.z); u.w = bfbits(v.w);
  ((ushort4*)out)[i] = u;
}

// ---------------------------------------------------------------- bias concat (fp32)
__global__ void concat_bias(const float* __restrict__ bq, const float* __restrict__ bk,
                            const float* __restrict__ bv, float* __restrict__ out) {
  int i = blockIdx.x * 256 + threadIdx.x;  // 6144 total
  float v = (i < 4096) ? bq[i] : ((i < 5120) ? bk[i - 4096] : bv[i - 5120]);
  out[i] = v;
}

// ---------------------------------------------------------------- V transpose
// V lives in QKV at col 5120: [token][6144]. out VT: [(b*8+kvh)][128][2048]
__global__ void transpose_v(const __hip_bfloat16* __restrict__ QKV,
                            __hip_bfloat16* __restrict__ VT) {
  __shared__ __hip_bfloat16 tile[32][33];
  int z = blockIdx.z, b = z >> 3, kvh = z & 7;
  int s0 = blockIdx.x * 32, h0 = blockIdx.y * 32;
  int tx = threadIdx.x, ty = threadIdx.y;
#pragma unroll
  for (int ry = ty; ry < 32; ry += 8)
    tile[ry][tx] =
        QKV[(long)(b * 2048 + s0 + ry) * 6144 + 5120 + kvh * 128 + h0 + tx];
  __syncthreads();
#pragma unroll
  for (int ry = ty; ry < 32; ry += 8)
    VT[((long)z * 128 + h0 + ry) * 2048 + s0 + tx] = tile[tx][ry];
}

// ---------------------------------------------------------------- GEMM  C = A * W^T + bias
// A: MxK bf16 row-major, W: NxK bf16 row-major. 128x128 tile, BK=32, 256 thr.
// GROUP_M=8 block swizzle for L2 locality. ROPE=1: apply RoPE to cols<5120 in epilogue.
template <int OUT_F32, int ROPE>
__global__ void __launch_bounds__(256) gemm_bt(const __hip_bfloat16* __restrict__ A,
                                               const __hip_bfloat16* __restrict__ W,
                                               const float* __restrict__ bias,
                                               const float* __restrict__ fc,
                                               const int* __restrict__ startpos,
                                               void* __restrict__ Cout,
                                               int M, int N, int K) {
  __shared__ __align__(16) char As[8192];
  __shared__ __align__(16) char Bs[8192];
  const int t = threadIdx.x, w = t >> 6, l = t & 63, quad = l >> 4, lan = l & 15;
  // GROUP_M swizzle: consecutive pids walk 8 m-rows per n-col
  int pid = blockIdx.x + blockIdx.y * gridDim.x;
  int width = (int)gridDim.x << 3;
  int group = pid / width;
  int rem = (int)gridDim.y - (group << 3);
  int gsz = rem < 8 ? rem : 8;
  int pm = (group << 3) + (pid % gsz);
  int pn = (pid % width) / gsz;
  const int bm = pm << 7, bn = pn << 7;
  const int wr = (w >> 1) << 6, wc = (w & 1) << 6;
  f32x4 acc[4][4] = {};

  const char* Ag0 = (const char*)(A + (long)(bm + (w << 4) + (l >> 2)) * K) + (l & 3) * 16;
  const char* Ag1 = (const char*)(A + (long)(bm + ((w + 4) << 4) + (l >> 2)) * K) + (l & 3) * 16;
  const char* Bg0 = (const char*)(W + (long)(bn + (w << 4) + (l >> 2)) * K) + (l & 3) * 16;
  const char* Bg1 = (const char*)(W + (long)(bn + ((w + 4) << 4) + (l >> 2)) * K) + (l & 3) * 16;
  char* AsW0 = As + (w << 10);
  char* AsW1 = As + ((w + 4) << 10);
  char* BsW0 = Bs + (w << 10);
  char* BsW1 = Bs + ((w + 4) << 10);

  for (int k0 = 0; k0 < K; k0 += 32) {
    g2lds16(Ag0 + k0 * 2, AsW0);
    g2lds16(Ag1 + k0 * 2, AsW1);
    g2lds16(Bg0 + k0 * 2, BsW0);
    g2lds16(Bg1 + k0 * 2, BsW1);
    __syncthreads();
    bf16x8 a[4], b[4];
#pragma unroll
    for (int i = 0; i < 4; i++)
      a[i] = *(const bf16x8*)(As + ((wr + (i << 4) + lan) << 6) + (quad << 4));
#pragma unroll
    for (int j = 0; j < 4; j++)
      b[j] = *(const bf16x8*)(Bs + ((wc + (j << 4) + lan) << 6) + (quad << 4));
#pragma unroll
    for (int i = 0; i < 4; i++)
#pragma unroll
      for (int j = 0; j < 4; j++)
        acc[i][j] = MFMA(a[i], b[j], acc[i][j]);
    __syncthreads();
  }

  float bv[4];
#pragma unroll
  for (int j = 0; j < 4; j++) bv[j] = bias[bn + wc + (j << 4) + lan];
  const bool dorope = ROPE && (bn < 5120);  // block-uniform
  int sp = 0;
  if (ROPE && dorope) sp = startpos[0];
#pragma unroll
  for (int i = 0; i < 4; i++) {
#pragma unroll
    for (int e = 0; e < 4; e++) {
      long row = bm + wr + (i << 4) + (quad << 2) + e;
      const float2* fc2 = (const float2*)fc + ((long)(sp + (int)(row & 2047)) << 6);
#pragma unroll
      for (int j = 0; j < 4; j++) {
        float v = acc[i][j][e] + bv[j];
        long col = bn + wc + (j << 4) + lan;
        if (ROPE && dorope) {
          float p = __shfl_xor(v, 1);  // pair partner: cols (2m,2m+1) = lanes (even,odd)
          float2 cs2 = fc2[((int)col >> 1) & 63];
          v = (lan & 1) ? (p * cs2.y + v * cs2.x) : (v * cs2.x - p * cs2.y);
        }
        if (OUT_F32)
          ((float*)Cout)[row * N + col] = v;
        else
          ((__hip_bfloat16*)Cout)[row * N + col] = __float2bfloat16(v);
      }
    }
  }
}

// ---------------------------------------------------------------- flash staging helpers
__device__ __forceinline__ void stage_k(const __hip_bfloat16* QKV, char* buf,
                                        int b, int S, int t0, int kvh, int w, int l) {
  int rl = l >> 4, cd = l & 15;
#pragma unroll
  for (int ii = 0; ii < 4; ii++) {
    int i = (w << 2) + ii;
    int r = (i << 2) + rl;
    int cs = cd ^ (r & 15);
    const char* g =
        (const char*)(QKV + (long)(b * S + t0 + r) * 6144 + 4096 + kvh * 128) + (cs << 4);
    g2lds16(g, buf + (i << 10));
  }
}
__device__ __forceinline__ void stage_v(const __hip_bfloat16* VT, char* Vs,
                                        int b, int S, int t0, int kvh, int w, int l) {
  int dl = l >> 3, cd2 = l & 7;
#pragma unroll
  for (int ii = 0; ii < 4; ii++) {
    int i = (w << 2) + ii;
    int d = (i << 3) + dl;
    int cs = cd2 ^ dl;
    const char* g =
        (const char*)(VT + ((long)((b << 3) + kvh) * 128 + d) * S + t0) + (cs << 4);
    g2lds16(g, Vs + (i << 10));
  }
}

// ---------------------------------------------------------------- flash attention (S^T form)
// QKV: [token][6144] (Q 0..4095 rope'd, K 4096..5119 rope'd), VT: [(b*8+kvh)][128][2048]
// Ctx: [token][4096]. grid (16, 32, 2), 256 thr. Double-buffered K staging; V staged
// under QK+softmax cover with fine vmcnt(4) wait; P stays fully in-register via a
// K-dim permutation pi(k) shared by the PV A (V) and B (P) operands.
__global__ void __launch_bounds__(256, 3) flash_attn(const __hip_bfloat16* __restrict__ QKV,
                                                     const __hip_bfloat16* __restrict__ VT,
                                                     __hip_bfloat16* __restrict__ Ctx, int S) {
  __shared__ __align__(16) char smem[49152];
  char* Vs = smem + 32768;  // 16KB V^T tile [128][128B] swizzled; smem[0..32K) = K dbuf / Q preload
  const int t = threadIdx.x, w = t >> 6, l = t & 63, quad = l >> 4, lan = l & 15;
  const int b = blockIdx.z, qh = blockIdx.y, kvh = qh >> 2;
  const int q0idx = (int)gridDim.x - 1 - blockIdx.x;  // heavy blocks dispatch first
  const int q0 = q0idx << 7;
  const float cl = 0.08838834764831845f * 1.4426950408889634f;  // 1/sqrt(128) * log2(e)

  // preload 128-row Q tile into smem[0..32K), chunk-swizzled (c ^ row&15)
  {
    int rl = l >> 4, cd = l & 15;
#pragma unroll
    for (int ii = 0; ii < 8; ii++) {
      int i = (w << 3) + ii;
      int r = (i << 2) + rl;
      int cs = cd ^ (r & 15);
      const char* g =
          (const char*)(QKV + (long)(b * S + q0 + r) * 6144 + qh * 128) + (cs << 4);
      g2lds16(g, smem + (i << 10));
    }
  }
  __syncthreads();
  bf16x8 qf[2][4];
#pragma unroll
  for (int st = 0; st < 2; st++) {
    int row = ((((w << 1) + st) << 4) + lan);
#pragma unroll
    for (int ks = 0; ks < 4; ks++)
      qf[st][ks] = *(const bf16x8*)(smem + (row << 8) + ((((ks << 2) + quad) ^ lan) << 4));
  }
  __syncthreads();  // qf landed in regs; safe to overwrite Q region

  f32x4 o[2][8] = {};
  float m0[2] = {-__builtin_inff(), -__builtin_inff()};
  float lsum[2] = {0.f, 0.f};
  const int ntiles = (q0idx << 1) + 2;

  stage_k(QKV, smem, b, S, 0, kvh, w, l);  // K(0) -> buf0

  for (int kt = 0; kt < ntiles; kt++) {
    const int t0 = kt << 6;
    __syncthreads();  // drains vmcnt(0): K(kt) arrived; Vs reads of kt-1 done
    stage_v(VT, Vs, b, S, t0, kvh, w, l);  // 4 loads: covered by QK+softmax
    const bool more = (kt + 1 < ntiles);
    if (more) stage_k(QKV, smem + (((kt + 1) & 1) << 14), b, S, t0 + 64, kvh, w, l);
    const char* Kbuf = smem + ((kt & 1) << 14);

    // S^T[t][q] = K·Q^T : 4 j-tiles (t), each K frag feeds both strips
    f32x4 sa[2][4] = {{}, {}};
#pragma unroll
    for (int j = 0; j < 4; j++)
#pragma unroll
      for (int ks = 0; ks < 4; ks++) {
        bf16x8 kf = *(const bf16x8*)(Kbuf + (((j << 4) + lan) << 8) +
                                     ((((ks << 2) + quad) ^ lan) << 4));
        sa[0][j] = MFMA(kf, qf[0][ks], sa[0][j]);
        sa[1][j] = MFMA(kf, qf[1][ks], sa[1][j]);
      }

    // softmax + in-lane P pack.  pk[st][j] = {pack(p0,p1), pack(p2,p3)}
    uint pk[2][4][2];
#pragma unroll
    for (int st = 0; st < 2; st++) {
      const int strip = (w << 1) + st;
      const int qg = q0 + (strip << 4) + lan;
      if (t0 + 63 > q0 + (strip << 4)) {
#pragma unroll
        for (int j = 0; j < 4; j++)
#pragma unroll
          for (int e = 0; e < 4; e++)
            if (t0 + (j << 4) + (quad << 2) + e > qg) sa[st][j][e] = -1e30f;
      }
      float mq = sa[st][0][0];
#pragma unroll
      for (int j = 0; j < 4; j++)
#pragma unroll
        for (int e = 0; e < 4; e++) mq = fmaxf(mq, sa[st][j][e]);
      mq = fmaxf(mq, __shfl_xor(mq, 16));
      mq = fmaxf(mq, __shfl_xor(mq, 32));
      float mn = fmaxf(m0[st], mq);
      float al = exp2f((m0[st] - mn) * cl);
      m0[st] = mn;
      float rs = 0.f;
#pragma unroll
      for (int j = 0; j < 4; j++) {
        float p0 = exp2f((sa[st][j][0] - mn) * cl);
        float p1 = exp2f((sa[st][j][1] - mn) * cl);
        float p2 = exp2f((sa[st][j][2] - mn) * cl);
        float p3 = exp2f((sa[st][j][3] - mn) * cl);
        rs += (p0 + p1) + (p2 + p3);
        pk[st][j][0] = (uint)bfbits(p0) | ((uint)bfbits(p1) << 16);
        pk[st][j][1] = (uint)bfbits(p2) | ((uint)bfbits(p3) << 16);
      }
      rs += __shfl_xor(rs, 16);
      rs += __shfl_xor(rs, 32);
      lsum[st] = lsum[st] * al + rs;
#pragma unroll
      for (int dt = 0; dt < 8; dt++) o[st][dt] *= al;
    }
    // P as B-operand under pi: elem jj<4 -> t=32c+4*quad+jj (=sa[2c][jj] of THIS lane),
    // jj>=4 -> t=32c+16+4*quad+(jj-4) (=sa[2c+1][jj-4]).  Fully in-lane.
    bf16x8 pf[2][2];
#pragma unroll
    for (int st = 0; st < 2; st++)
#pragma unroll
      for (int c = 0; c < 2; c++) {
        uint4 u;
        u.x = pk[st][2 * c][0];
        u.y = pk[st][2 * c][1];
        u.z = pk[st][2 * c + 1][0];
        u.w = pk[st][2 * c + 1][1];
        pf[st][c] = __builtin_bit_cast(bf16x8, u);
      }

    asm volatile("" ::: "memory");
    if (more)
      __builtin_amdgcn_s_waitcnt(0x0F74);  // vmcnt(4): V done, K(kt+1) still in flight
    else
      __builtin_amdgcn_s_waitcnt(0x0F70);  // vmcnt(0)
    __builtin_amdgcn_s_barrier();          // all waves' V staged
    asm volatile("" ::: "memory");

    // O^T += V^T · P^T with matching pi on A: two 8B chunks at t-offsets 32c+4q, +16
#pragma unroll
    for (int dt = 0; dt < 8; dt++) {
      const int drow = (dt << 4) + lan;
      const char* rowp = Vs + (drow << 7);
      const int k8 = drow & 7;
#pragma unroll
      for (int c = 0; c < 2; c++) {
        const int g0 = (c << 2) + (quad >> 1);
        const int h0 = (quad & 1) << 3;
        uint2 lo = *(const uint2*)(rowp + (((g0 ^ k8) << 4) + h0));
        uint2 hi = *(const uint2*)(rowp + ((((g0 + 2) ^ k8) << 4) + h0));
        uint4 u;
        u.x = lo.x; u.y = lo.y; u.z = hi.x; u.w = hi.y;
        bf16x8 vf = __builtin_bit_cast(bf16x8, u);
        o[0][dt] = MFMA(vf, pf[0][c], o[0][dt]);
        o[1][dt] = MFMA(vf, pf[1][c], o[1][dt]);
      }
    }
  }

  // epilogue: lane holds q = strip*16+lan, d = dt*16+quad*4+e -> packed 8B stores
#pragma unroll
  for (int st = 0; st < 2; st++) {
    float inv = 1.0f / lsum[st];
    int strip = (w << 1) + st;
    long token = (long)b * S + q0 + (strip << 4) + lan;
    __hip_bfloat16* obase = Ctx + token * 4096 + qh * 128;
#pragma unroll
    for (int dt = 0; dt < 8; dt++) {
      ushort4 u;
      u.x = bfbits(o[st][dt][0] * inv);
      u.y = bfbits(o[st][dt][1] * inv);
      u.z = bfbits(o[st][dt][2] * inv);
      u.w = bfbits(o[st][dt][3] * inv);
      *(ushort4*)(obase + (dt << 4) + (quad << 2)) = u;
    }
  }
}

// ---------------------------------------------------------------- launch
extern "C" void kernel_launch(void* const* d_in, const int* in_sizes, int n_in,
                              void* d_out, int out_size, void* d_ws, size_t ws_size,
                              hipStream_t stream) {
  const float* xs = (const float*)d_in[0];
  const int* startpos = (const int*)d_in[1];
  const float* fc = (const float*)d_in[2];
  const float* Wq = (const float*)d_in[3];
  const float* bq = (const float*)d_in[4];
  const float* Wk = (const float*)d_in[5];
  const float* bk = (const float*)d_in[6];
  const float* Wv = (const float*)d_in[7];
  const float* bv = (const float*)d_in[8];
  const float* Wo = (const float*)d_in[9];
  const float* bo = (const float*)d_in[10];
  float* out = (float*)d_out;
  char* ws = (char*)d_ws;

  __hip_bfloat16* Wqkvb = (__hip_bfloat16*)(ws);               // 48MB [6144][4096]
  __hip_bfloat16* Xb    = (__hip_bfloat16*)(ws + 50331648L);   // 32MB [4096][4096]
  __hip_bfloat16* QKVb  = (__hip_bfloat16*)(ws + 83886080L);   // 48MB [4096][6144]
  __hip_bfloat16* VbT   = (__hip_bfloat16*)(ws + 134217728L);  // 8MB  [16][128][2048]
  float*          bqkv  = (float*)(ws + 142606336L);           // 24KB
  __hip_bfloat16* Wob   = Wqkvb;  // reused after QKV GEMM
  __hip_bfloat16* Ctx   = Xb;     // reused after QKV GEMM

  cvt_f32_bf16<<<16384, 256, 0, stream>>>(xs, Xb, 4194304);
  cvt_f32_bf16<<<16384, 256, 0, stream>>>(Wq, Wqkvb, 4194304);
  cvt_f32_bf16<<<4096, 256, 0, stream>>>(Wk, Wqkvb + 16777216L, 1048576);
  cvt_f32_bf16<<<4096, 256, 0, stream>>>(Wv, Wqkvb + 20971520L, 1048576);
  concat_bias<<<24, 256, 0, stream>>>(bq, bk, bv, bqkv);

  // QKV projection with fused RoPE on Q/K columns
  gemm_bt<0, 1><<<dim3(48, 32), 256, 0, stream>>>(Xb, Wqkvb, bqkv, fc, startpos, QKVb,
                                                  4096, 6144, 4096);

  transpose_v<<<dim3(64, 4, 16), dim3(32, 8), 0, stream>>>(QKVb, VbT);
  cvt_f32_bf16<<<16384, 256, 0, stream>>>(Wo, Wob, 4194304);  // aliases Wqkvb (post-GEMM)

  flash_attn<<<dim3(16, 32, 2), 256, 0, stream>>>(QKVb, VbT, Ctx, 2048);

  gemm_bt<1, 0><<<dim3(32, 32), 256, 0, stream>>>(Ctx, Wob, bo, fc, startpos, out,
                                                  4096, 4096, 4096);
}